// Round 11
// baseline (154.391 us; speedup 1.0000x reference)
//
#include <hip/hip_runtime.h>
#include <hip/hip_bf16.h>
#include <cmath>

#define NN 8192
#define FIN 256
#define FOUT 128
#define NCH 8
#define JC (NN / NCH)        // 1024 j per chunk
#define WPC (JC / 64)        // 16 windows per chunk
#define MPITCH 18            // LDS mask row pitch (u64), padded

typedef short short8 __attribute__((ext_vector_type(8)));
typedef float f32x16 __attribute__((ext_vector_type(16)));
typedef unsigned long long u64;

static __device__ __forceinline__ unsigned short f2bf(float f) {
    unsigned u = __float_as_uint(f);
    u += 0x7fffu + ((u >> 16) & 1u);
    return (unsigned short)(u >> 16);
}

// ---------------------------------------------------------------------------
// Compress: adj (256MB int32) -> bm3 (8MB u64), layout [chunk][row][winc].
// Word bit (16c+q) <-> col (ch*16+winc)*64 + 4q + c. 256B contiguous/thread.
// ---------------------------------------------------------------------------
__global__ __launch_bounds__(256)
void gat_compress(const int* __restrict__ adj, u64* __restrict__ bm3) {
    const int t = threadIdx.x;
    const int row = blockIdx.x * 2 + (t >> 7);
    const int wing = t & 127;
    const int4* p = (const int4*)(adj + (size_t)row * NN + wing * 64);
    u64 m = 0;
    #pragma unroll
    for (int q = 0; q < 16; ++q) {
        const int4 v = p[q];
        m |= (u64)(v.x > 0) << q;
        m |= (u64)(v.y > 0) << (16 + q);
        m |= (u64)(v.z > 0) << (32 + q);
        m |= (u64)(v.w > 0) << (48 + q);
    }
    const int ch = wing >> 4, winc = wing & 15;
    bm3[((size_t)ch * NN + row) * 16 + winc] = m;
}

// ---------------------------------------------------------------------------
// Pass A: h = input @ W^T + Wb (bf16 MFMA). hT3 in exact MFMA A-frag order.
// s = h·a1, t = h·a2 + ab.
// ---------------------------------------------------------------------------
__global__ __launch_bounds__(256, 2)
void gat_pass_a(const float* __restrict__ input, const float* __restrict__ W,
                const float* __restrict__ Wb, const float* __restrict__ aw,
                const float* __restrict__ ab, unsigned short* __restrict__ hT3,
                float* __restrict__ s_out, float* __restrict__ t_out) {
    const int tid = threadIdx.x;
    const int w = tid >> 6, l = tid & 63;
    const int l5 = l >> 5, l31 = l & 31;
    const int nt = w >> 1, mh = w & 1;
    const int bx = blockIdx.x;
    const int i = bx * 64 + nt * 32 + l31;

    f32x16 acc0 = {}; f32x16 acc1 = {};
    #pragma unroll
    for (int ks = 0; ks < FIN / 16; ++ks) {
        const int c0 = ks * 16 + l5 * 8;
        const float4 b0 = *(const float4*)(input + (size_t)i * FIN + c0);
        const float4 b1 = *(const float4*)(input + (size_t)i * FIN + c0 + 4);
        short8 bf;
        bf[0]=(short)f2bf(b0.x); bf[1]=(short)f2bf(b0.y); bf[2]=(short)f2bf(b0.z); bf[3]=(short)f2bf(b0.w);
        bf[4]=(short)f2bf(b1.x); bf[5]=(short)f2bf(b1.y); bf[6]=(short)f2bf(b1.z); bf[7]=(short)f2bf(b1.w);
        {
            const int kcol = l31 + 32 * (2 * mh + 0);
            const float4 a0 = *(const float4*)(W + (size_t)kcol * FIN + c0);
            const float4 a1 = *(const float4*)(W + (size_t)kcol * FIN + c0 + 4);
            short8 af;
            af[0]=(short)f2bf(a0.x); af[1]=(short)f2bf(a0.y); af[2]=(short)f2bf(a0.z); af[3]=(short)f2bf(a0.w);
            af[4]=(short)f2bf(a1.x); af[5]=(short)f2bf(a1.y); af[6]=(short)f2bf(a1.z); af[7]=(short)f2bf(a1.w);
            acc0 = __builtin_amdgcn_mfma_f32_32x32x16_bf16(af, bf, acc0, 0, 0, 0);
        }
        {
            const int kcol = l31 + 32 * (2 * mh + 1);
            const float4 a0 = *(const float4*)(W + (size_t)kcol * FIN + c0);
            const float4 a1 = *(const float4*)(W + (size_t)kcol * FIN + c0 + 4);
            short8 af;
            af[0]=(short)f2bf(a0.x); af[1]=(short)f2bf(a0.y); af[2]=(short)f2bf(a0.z); af[3]=(short)f2bf(a0.w);
            af[4]=(short)f2bf(a1.x); af[5]=(short)f2bf(a1.y); af[6]=(short)f2bf(a1.z); af[7]=(short)f2bf(a1.w);
            acc1 = __builtin_amdgcn_mfma_f32_32x32x16_bf16(af, bf, acc1, 0, 0, 0);
        }
    }
    __shared__ float sred[4][32];
    __shared__ float tred[4][32];
    float sacc = 0.f, tacc = 0.f;
    const int jloc = nt * 32 + l31;
    const int ksb = jloc >> 4;
    const int lane_j = 32 * ((jloc >> 3) & 1);
    const int e = jloc & 7;
    #pragma unroll
    for (int m = 0; m < 2; ++m) {
        #pragma unroll
        for (int r = 0; r < 16; ++r) {
            const int kcol = 32 * (2 * mh + m) + 4 * l5 + (r & 3) + 8 * (r >> 2);
            const float hv = (m ? acc1[r] : acc0[r]) + Wb[kcol];
            const int fg = kcol >> 5;
            const int lane = (kcol & 31) + lane_j;
            hT3[((((size_t)bx * 4 + fg) * 4 + ksb) * 64 + lane) * 8 + e] = f2bf(hv);
            sacc += hv * aw[kcol];
            tacc += hv * aw[FOUT + kcol];
        }
    }
    sacc += __shfl_xor(sacc, 32);
    tacc += __shfl_xor(tacc, 32);
    if (l < 32) { sred[w][l] = sacc; tred[w][l] = tacc; }
    __syncthreads();
    if (mh == 0 && l < 32) {
        s_out[i] = sred[w][l] + sred[w + 1][l];
        t_out[i] = tred[w][l] + tred[w + 1][l] + ab[0];
    }
}

// ---------------------------------------------------------------------------
// Pass B: barrier-free, wave-owns-32-rows, SOFTWARE-PIPELINED: each step
// issues the NEXT step's 4 frag loads + 2 t loads before computing the
// current step, via static A/B register ping-pong (no copies). Masks staged
// once in LDS. Epilogue: direct coalesced stores (no cross-wave reduce).
// ---------------------------------------------------------------------------
#define LOADF(SUF, WIN, KS)                                                     \
    {                                                                           \
        const int jw_ = jb + (WIN) * 64;                                        \
        const unsigned short* hp_ =                                            \
            hT3 + ((size_t)((jw_ >> 6) * 16 + (KS))) * 512 + (size_t)l * 8;    \
        a0##SUF = *(const short8*)(hp_);                                        \
        a1##SUF = *(const short8*)(hp_ + 2048);                                 \
        a2##SUF = *(const short8*)(hp_ + 4096);                                 \
        a3##SUF = *(const short8*)(hp_ + 6144);                                 \
        const int jsl_ = jw_ + (KS) * 16 + l5 * 8;                              \
        t0##SUF = *(const float4*)(t_in + jsl_);                                \
        t1##SUF = *(const float4*)(t_in + jsl_ + 4);                            \
    }

#define COMPUTE(SUF, MW, KS)                                                    \
    {                                                                           \
        const u64 m = (MW) >> ((KS) * 4 + l5 * 2);                              \
        short8 bf;                                                              \
        float x, p;                                                             \
        x = si + t0##SUF.x; x = fmaxf(x, 0.2f * x); p = __expf(x);              \
        p = ((m >> 0)  & 1ull) ? p : 0.f; dacc += p; bf[0] = (short)f2bf(p);    \
        x = si + t0##SUF.y; x = fmaxf(x, 0.2f * x); p = __expf(x);              \
        p = ((m >> 16) & 1ull) ? p : 0.f; dacc += p; bf[1] = (short)f2bf(p);    \
        x = si + t0##SUF.z; x = fmaxf(x, 0.2f * x); p = __expf(x);              \
        p = ((m >> 32) & 1ull) ? p : 0.f; dacc += p; bf[2] = (short)f2bf(p);    \
        x = si + t0##SUF.w; x = fmaxf(x, 0.2f * x); p = __expf(x);              \
        p = ((m >> 48) & 1ull) ? p : 0.f; dacc += p; bf[3] = (short)f2bf(p);    \
        x = si + t1##SUF.x; x = fmaxf(x, 0.2f * x); p = __expf(x);              \
        p = ((m >> 1)  & 1ull) ? p : 0.f; dacc += p; bf[4] = (short)f2bf(p);    \
        x = si + t1##SUF.y; x = fmaxf(x, 0.2f * x); p = __expf(x);              \
        p = ((m >> 17) & 1ull) ? p : 0.f; dacc += p; bf[5] = (short)f2bf(p);    \
        x = si + t1##SUF.z; x = fmaxf(x, 0.2f * x); p = __expf(x);              \
        p = ((m >> 33) & 1ull) ? p : 0.f; dacc += p; bf[6] = (short)f2bf(p);    \
        x = si + t1##SUF.w; x = fmaxf(x, 0.2f * x); p = __expf(x);              \
        p = ((m >> 49) & 1ull) ? p : 0.f; dacc += p; bf[7] = (short)f2bf(p);    \
        acc0 = __builtin_amdgcn_mfma_f32_32x32x16_bf16(a0##SUF, bf, acc0, 0, 0, 0); \
        acc1 = __builtin_amdgcn_mfma_f32_32x32x16_bf16(a1##SUF, bf, acc1, 0, 0, 0); \
        acc2 = __builtin_amdgcn_mfma_f32_32x32x16_bf16(a2##SUF, bf, acc2, 0, 0, 0); \
        acc3 = __builtin_amdgcn_mfma_f32_32x32x16_bf16(a3##SUF, bf, acc3, 0, 0, 0); \
    }

__global__ __launch_bounds__(256, 2)
void gat_pass_b(const u64* __restrict__ bm3, const unsigned short* __restrict__ hT3,
                const float* __restrict__ s_in, const float* __restrict__ t_in,
                float* __restrict__ numw, float* __restrict__ dpart) {
    __shared__ u64 mlds[128 * MPITCH];       // 18 KB
    const int tid = threadIdx.x;
    const int wv = tid >> 6, l = tid & 63;
    const int l5 = l >> 5, l31 = l & 31;
    const int i0 = blockIdx.x * 128;
    const int chunk = blockIdx.y;
    const int jb = chunk * JC;

    // ---- stage masks: 16KB contiguous -> LDS [128][18] (one barrier) ----
    {
        const uint4* src = (const uint4*)(bm3 + ((size_t)chunk * NN + i0) * 16) + tid * 4;
        const uint4 q0 = src[0], q1 = src[1], q2 = src[2], q3 = src[3];
        u64* dst = mlds + (tid >> 1) * MPITCH + (tid & 1) * 8;
        *(uint4*)(dst)     = q0;
        *(uint4*)(dst + 2) = q1;
        *(uint4*)(dst + 4) = q2;
        *(uint4*)(dst + 6) = q3;
    }
    const int lrow = wv * 32 + l31;
    const float si = s_in[i0 + lrow];
    __syncthreads();

    f32x16 acc0 = {}, acc1 = {}, acc2 = {}, acc3 = {};
    float dacc = 0.f;

    short8 a0A, a1A, a2A, a3A, a0B, a1B, a2B, a3B;
    float4 t0A, t1A, t0B, t1B;

    u64 mw_nxt = mlds[lrow * MPITCH];        // window 0 mask
    LOADF(A, 0, 0)

    for (int win = 0; win < WPC; ++win) {
        const u64 mcur = mw_nxt;
        const int wn = (win + 1 < WPC) ? win + 1 : win;
        mw_nxt = mlds[lrow * MPITCH + wn];
        LOADF(B, win, 1) COMPUTE(A, mcur, 0)
        LOADF(A, win, 2) COMPUTE(B, mcur, 1)
        LOADF(B, win, 3) COMPUTE(A, mcur, 2)
        LOADF(A, wn, 0)  COMPUTE(B, mcur, 3)
    }

    // ---- epilogue: direct coalesced stores (no reduction, no barrier) ----
    float* nb = numw + (size_t)chunk * FOUT * NN;
    const int irow = i0 + lrow;
    #pragma unroll
    for (int r = 0; r < 16; ++r) {
        const int fr = (r & 3) + 8 * (r >> 2) + 4 * l5;
        nb[(size_t)(fr      ) * NN + irow] = acc0[r];
        nb[(size_t)(fr +  32) * NN + irow] = acc1[r];
        nb[(size_t)(fr +  64) * NN + irow] = acc2[r];
        nb[(size_t)(fr +  96) * NN + irow] = acc3[r];
    }
    dacc += __shfl_xor(dacc, 32);
    if (l5 == 0) dpart[(size_t)chunk * NN + irow] = dacc;
}

// ---------------------------------------------------------------------------
// Pass C: out[i][f] = elu( sum_c numw[c][f][i] / sum_c dpart[c][i] )
// ---------------------------------------------------------------------------
__global__ __launch_bounds__(256)
void gat_reduce(const float* __restrict__ numw, const float* __restrict__ dpart,
                float* __restrict__ out, int nchunk) {
    __shared__ float tile[FOUT * 33];
    __shared__ float dent[32];
    const int t = threadIdx.x;
    const int i0 = blockIdx.x * 32;
    if (t < 32) {
        float d = 0.f;
        for (int c = 0; c < nchunk; ++c) d += dpart[(size_t)c * NN + i0 + t];
        dent[t] = d;
    }
    __syncthreads();
    #pragma unroll
    for (int e = 0; e < 4; ++e) {
        const int f = e * 32 + (t >> 3);
        const int io = (t & 7) * 4;
        float4 s = {0.f, 0.f, 0.f, 0.f};
        for (int c = 0; c < nchunk; ++c) {
            const float4 v = *(const float4*)(numw + ((size_t)c * FOUT + f) * NN + i0 + io);
            s.x += v.x; s.y += v.y; s.z += v.z; s.w += v.w;
        }
        float v;
        v = s.x / dent[io + 0]; tile[f * 33 + io + 0] = (v > 0.f) ? v : expm1f(v);
        v = s.y / dent[io + 1]; tile[f * 33 + io + 1] = (v > 0.f) ? v : expm1f(v);
        v = s.z / dent[io + 2]; tile[f * 33 + io + 2] = (v > 0.f) ? v : expm1f(v);
        v = s.w / dent[io + 3]; tile[f * 33 + io + 3] = (v > 0.f) ? v : expm1f(v);
    }
    __syncthreads();
    #pragma unroll
    for (int e = 0; e < 4; ++e) {
        const int row = (t >> 5) * 4 + e;
        const int fo = (t & 31) * 4;
        const float4 v = { tile[(fo + 0) * 33 + row], tile[(fo + 1) * 33 + row],
                           tile[(fo + 2) * 33 + row], tile[(fo + 3) * 33 + row] };
        *(float4*)(out + (size_t)(i0 + row) * FOUT + fo) = v;
    }
}

// ---------------------------------------------------------------------------
extern "C" void kernel_launch(void* const* d_in, const int* in_sizes, int n_in,
                              void* d_out, int out_size, void* d_ws, size_t ws_size,
                              hipStream_t stream) {
    const float* input = (const float*)d_in[0];
    const int*   adj   = (const int*)d_in[1];
    const float* Ww    = (const float*)d_in[2];
    const float* Wb    = (const float*)d_in[3];
    const float* aw    = (const float*)d_in[4];
    const float* ab    = (const float*)d_in[5];
    float* out = (float*)d_out;

    char* ws = (char*)d_ws;
    unsigned short* hT3 = (unsigned short*)ws;               // 2 MB
    float* s_buf = (float*)(ws + (size_t)FOUT * NN * 2);     // 32 KB
    float* t_buf = s_buf + NN;                               // 32 KB
    float* dpart = t_buf + NN;                               // NCH*32 KB
    float* numw = dpart + (size_t)NCH * NN;                  // NCH*4 MB
    u64* bm3 = (u64*)(numw + (size_t)NCH * NN * FOUT);       // 8 MB

    gat_pass_a<<<dim3(NN / 64), 256, 0, stream>>>(input, Ww, Wb, aw, ab, hT3, s_buf, t_buf);
    gat_compress<<<dim3(NN / 2), 256, 0, stream>>>(adj, bm3);
    gat_pass_b<<<dim3(NN / 128, NCH), 256, 0, stream>>>(bm3, hT3, s_buf, t_buf, numw, dpart);
    gat_reduce<<<dim3(NN / 32), 256, 0, stream>>>(numw, dpart, out, NCH);
}

// Round 12
// 145.518 us; speedup vs baseline: 1.0610x; 1.0610x over previous
//
#include <hip/hip_runtime.h>
#include <hip/hip_bf16.h>
#include <cmath>

#define NN 8192
#define FIN 256
#define FOUT 128
#define NCH 8
#define JC (NN / NCH)        // 1024 j per chunk
#define WPC (JC / 64)        // 16 windows (of 64 j) per chunk
#define MPITCH 17            // LDS mask row pitch (u64)
#define LOG2E 1.44269504f

typedef short short8 __attribute__((ext_vector_type(8)));
typedef float f32x4 __attribute__((ext_vector_type(4)));
typedef float f32x16 __attribute__((ext_vector_type(16)));
typedef unsigned long long u64;

static __device__ __forceinline__ unsigned short f2bf(float f) {
    unsigned u = __float_as_uint(f);
    u += 0x7fffu + ((u >> 16) & 1u);
    return (unsigned short)(u >> 16);
}

static __device__ __forceinline__ unsigned cvtpk(float lo, float hi) {
    unsigned r;
    asm("v_cvt_pk_bf16_f32 %0, %1, %2" : "=v"(r) : "v"(lo), "v"(hi));
    return r;
}

// ---------------------------------------------------------------------------
// Compress: adj (256MB int32) -> bm3 (8MB u64), layout [chunk][row][winc],
// PLAIN bit order: bit n of word = col win*64 + n. 256B contiguous/thread.
// ---------------------------------------------------------------------------
__global__ __launch_bounds__(256)
void gat_compress(const int* __restrict__ adj, u64* __restrict__ bm3) {
    const int t = threadIdx.x;
    const int row = blockIdx.x * 2 + (t >> 7);
    const int wing = t & 127;
    const int4* p = (const int4*)(adj + (size_t)row * NN + wing * 64);
    u64 m = 0;
    #pragma unroll
    for (int q = 0; q < 16; ++q) {
        const int4 v = p[q];
        m |= (u64)(v.x > 0) << (q * 4 + 0);
        m |= (u64)(v.y > 0) << (q * 4 + 1);
        m |= (u64)(v.z > 0) << (q * 4 + 2);
        m |= (u64)(v.w > 0) << (q * 4 + 3);
    }
    const int ch = wing >> 4, winc = wing & 15;
    bm3[((size_t)ch * NN + row) * 16 + winc] = m;
}

// ---------------------------------------------------------------------------
// Pass A: h = input @ W^T + Wb (bf16 MFMA). Writes hT4 in 16x16x32 A-frag
// order: element (f, j) at [((j>>5)*8 + (f>>4))*512 + ((f&15) + 16*((j&31)>>3))*8
// + (j&7)] so pass_b A-frag loads are 64-lane-contiguous 1KB.
// s = h·a1 * log2e,  t = (h·a2 + ab) * log2e  (exp -> exp2 domain).
// ---------------------------------------------------------------------------
__global__ __launch_bounds__(256, 2)
void gat_pass_a(const float* __restrict__ input, const float* __restrict__ W,
                const float* __restrict__ Wb, const float* __restrict__ aw,
                const float* __restrict__ ab, unsigned short* __restrict__ hT4,
                float* __restrict__ s_out, float* __restrict__ t_out) {
    const int tid = threadIdx.x;
    const int w = tid >> 6, l = tid & 63;
    const int l5 = l >> 5, l31 = l & 31;
    const int nt = w >> 1, mh = w & 1;
    const int bx = blockIdx.x;
    const int i = bx * 64 + nt * 32 + l31;

    f32x16 acc0 = {}; f32x16 acc1 = {};
    #pragma unroll
    for (int ks = 0; ks < FIN / 16; ++ks) {
        const int c0 = ks * 16 + l5 * 8;
        const float4 b0 = *(const float4*)(input + (size_t)i * FIN + c0);
        const float4 b1 = *(const float4*)(input + (size_t)i * FIN + c0 + 4);
        short8 bf;
        bf[0]=(short)f2bf(b0.x); bf[1]=(short)f2bf(b0.y); bf[2]=(short)f2bf(b0.z); bf[3]=(short)f2bf(b0.w);
        bf[4]=(short)f2bf(b1.x); bf[5]=(short)f2bf(b1.y); bf[6]=(short)f2bf(b1.z); bf[7]=(short)f2bf(b1.w);
        {
            const int kcol = l31 + 32 * (2 * mh + 0);
            const float4 a0 = *(const float4*)(W + (size_t)kcol * FIN + c0);
            const float4 a1 = *(const float4*)(W + (size_t)kcol * FIN + c0 + 4);
            short8 af;
            af[0]=(short)f2bf(a0.x); af[1]=(short)f2bf(a0.y); af[2]=(short)f2bf(a0.z); af[3]=(short)f2bf(a0.w);
            af[4]=(short)f2bf(a1.x); af[5]=(short)f2bf(a1.y); af[6]=(short)f2bf(a1.z); af[7]=(short)f2bf(a1.w);
            acc0 = __builtin_amdgcn_mfma_f32_32x32x16_bf16(af, bf, acc0, 0, 0, 0);
        }
        {
            const int kcol = l31 + 32 * (2 * mh + 1);
            const float4 a0 = *(const float4*)(W + (size_t)kcol * FIN + c0);
            const float4 a1 = *(const float4*)(W + (size_t)kcol * FIN + c0 + 4);
            short8 af;
            af[0]=(short)f2bf(a0.x); af[1]=(short)f2bf(a0.y); af[2]=(short)f2bf(a0.z); af[3]=(short)f2bf(a0.w);
            af[4]=(short)f2bf(a1.x); af[5]=(short)f2bf(a1.y); af[6]=(short)f2bf(a1.z); af[7]=(short)f2bf(a1.w);
            acc1 = __builtin_amdgcn_mfma_f32_32x32x16_bf16(af, bf, acc1, 0, 0, 0);
        }
    }
    __shared__ float sred[4][32];
    __shared__ float tred[4][32];
    float sacc = 0.f, tacc = 0.f;
    const int jt = bx * 2 + nt;                     // j-tile (32-wide)
    const int lane_half = 16 * (l31 >> 3);          // k-quarter bits of lane
    const int e4 = l31 & 7;
    #pragma unroll
    for (int m = 0; m < 2; ++m) {
        #pragma unroll
        for (int r = 0; r < 16; ++r) {
            const int kcol = 32 * (2 * mh + m) + 4 * l5 + (r & 3) + 8 * (r >> 2);
            const float hv = (m ? acc1[r] : acc0[r]) + Wb[kcol];
            const int lane4 = (kcol & 15) + lane_half;
            hT4[(size_t)(jt * 8 + (kcol >> 4)) * 512 + lane4 * 8 + e4] = f2bf(hv);
            sacc += hv * aw[kcol];
            tacc += hv * aw[FOUT + kcol];
        }
    }
    sacc += __shfl_xor(sacc, 32);
    tacc += __shfl_xor(tacc, 32);
    if (l < 32) { sred[w][l] = sacc; tred[w][l] = tacc; }
    __syncthreads();
    if (mh == 0 && l < 32) {
        s_out[i] = (sred[w][l] + sred[w + 1][l]) * LOG2E;
        t_out[i] = (tred[w][l] + tred[w + 1][l] + ab[0]) * LOG2E;
    }
}

// ---------------------------------------------------------------------------
// Pass B: 16x16x32 MFMA, wave owns 16 rows x 128 f (8 x f32x4 acc = 32 AGPR).
// 4 waves/block (64 rows), launch_bounds(256,4) -> 4 blocks/CU = 16 waves/CU.
// Barrier-free main loop; masks staged once in LDS; direct coalesced stores.
// ---------------------------------------------------------------------------
__global__ __launch_bounds__(256, 4)
void gat_pass_b(const u64* __restrict__ bm3, const unsigned short* __restrict__ hT4,
                const float* __restrict__ s_in, const float* __restrict__ t_in,
                float* __restrict__ numw, float* __restrict__ dpart) {
    __shared__ u64 mlds[64 * MPITCH];        // 8.5 KB
    const int tid = threadIdx.x;
    const int wv = tid >> 6, l = tid & 63;
    const int li = l & 15;                   // i within wave tile (D col)
    const int kq = l >> 4;                   // k-quarter (0..3)
    const int i0 = blockIdx.x * 64;
    const int chunk = blockIdx.y;
    const int jb = chunk * JC;

    // ---- stage masks: 8KB contiguous -> LDS [64][17] (one barrier) ----
    {
        const u64* src = bm3 + ((size_t)chunk * NN + i0) * 16 + (size_t)tid * 4;
        const uint4 q0 = ((const uint4*)src)[0];
        const uint4 q1 = ((const uint4*)src)[1];
        u64* dst = mlds + (tid >> 2) * MPITCH + (tid & 3) * 4;
        *(uint4*)(dst)     = q0;
        *(uint4*)(dst + 2) = q1;
    }
    const int lrow = wv * 16 + li;
    const float si = s_in[i0 + lrow];
    __syncthreads();

    f32x4 acc0 = {}, acc1 = {}, acc2 = {}, acc3 = {};
    f32x4 acc4 = {}, acc5 = {}, acc6 = {}, acc7 = {};
    float dacc = 0.f;

    for (int win = 0; win < WPC; ++win) {
        const u64 mword = mlds[lrow * MPITCH + win];
        const int jw = jb + win * 64;
        #pragma unroll
        for (int kk = 0; kk < 2; ++kk) {
            const int jt = (jw + kk * 32) >> 5;
            const unsigned short* hp = hT4 + (size_t)jt * 4096 + (size_t)l * 8;
            const short8 af0 = *(const short8*)(hp);
            const short8 af1 = *(const short8*)(hp + 512);
            const short8 af2 = *(const short8*)(hp + 1024);
            const short8 af3 = *(const short8*)(hp + 1536);
            const short8 af4 = *(const short8*)(hp + 2048);
            const short8 af5 = *(const short8*)(hp + 2560);
            const short8 af6 = *(const short8*)(hp + 3072);
            const short8 af7 = *(const short8*)(hp + 3584);
            const float4 t0 = *(const float4*)(t_in + jw + kk * 32 + kq * 8);
            const float4 t1 = *(const float4*)(t_in + jw + kk * 32 + kq * 8 + 4);
            const unsigned mk = (unsigned)(mword >> (kk * 32 + kq * 8)) & 0xffu;

            float x, p0, p1, p2, p3, p4, p5, p6, p7;
            x = si + t0.x; x = fmaxf(x, 0.2f * x); p0 = exp2f(x);
            p0 = (mk & 1u)   ? p0 : 0.f; dacc += p0;
            x = si + t0.y; x = fmaxf(x, 0.2f * x); p1 = exp2f(x);
            p1 = (mk & 2u)   ? p1 : 0.f; dacc += p1;
            x = si + t0.z; x = fmaxf(x, 0.2f * x); p2 = exp2f(x);
            p2 = (mk & 4u)   ? p2 : 0.f; dacc += p2;
            x = si + t0.w; x = fmaxf(x, 0.2f * x); p3 = exp2f(x);
            p3 = (mk & 8u)   ? p3 : 0.f; dacc += p3;
            x = si + t1.x; x = fmaxf(x, 0.2f * x); p4 = exp2f(x);
            p4 = (mk & 16u)  ? p4 : 0.f; dacc += p4;
            x = si + t1.y; x = fmaxf(x, 0.2f * x); p5 = exp2f(x);
            p5 = (mk & 32u)  ? p5 : 0.f; dacc += p5;
            x = si + t1.z; x = fmaxf(x, 0.2f * x); p6 = exp2f(x);
            p6 = (mk & 64u)  ? p6 : 0.f; dacc += p6;
            x = si + t1.w; x = fmaxf(x, 0.2f * x); p7 = exp2f(x);
            p7 = (mk & 128u) ? p7 : 0.f; dacc += p7;

            union { int4 i4; short8 s8; } bu;
            bu.i4.x = (int)cvtpk(p0, p1);
            bu.i4.y = (int)cvtpk(p2, p3);
            bu.i4.z = (int)cvtpk(p4, p5);
            bu.i4.w = (int)cvtpk(p6, p7);
            const short8 bf = bu.s8;

            acc0 = __builtin_amdgcn_mfma_f32_16x16x32_bf16(af0, bf, acc0, 0, 0, 0);
            acc1 = __builtin_amdgcn_mfma_f32_16x16x32_bf16(af1, bf, acc1, 0, 0, 0);
            acc2 = __builtin_amdgcn_mfma_f32_16x16x32_bf16(af2, bf, acc2, 0, 0, 0);
            acc3 = __builtin_amdgcn_mfma_f32_16x16x32_bf16(af3, bf, acc3, 0, 0, 0);
            acc4 = __builtin_amdgcn_mfma_f32_16x16x32_bf16(af4, bf, acc4, 0, 0, 0);
            acc5 = __builtin_amdgcn_mfma_f32_16x16x32_bf16(af5, bf, acc5, 0, 0, 0);
            acc6 = __builtin_amdgcn_mfma_f32_16x16x32_bf16(af6, bf, acc6, 0, 0, 0);
            acc7 = __builtin_amdgcn_mfma_f32_16x16x32_bf16(af7, bf, acc7, 0, 0, 0);
        }
    }

    // ---- epilogue: direct coalesced stores (no reduction, no barrier) ----
    float* nb = numw + (size_t)chunk * FOUT * NN;
    const int irow = i0 + lrow;
    #pragma unroll
    for (int r = 0; r < 4; ++r) {
        const int fr = kq * 4 + r;
        nb[(size_t)(fr      ) * NN + irow] = acc0[r];
        nb[(size_t)(fr + 16 ) * NN + irow] = acc1[r];
        nb[(size_t)(fr + 32 ) * NN + irow] = acc2[r];
        nb[(size_t)(fr + 48 ) * NN + irow] = acc3[r];
        nb[(size_t)(fr + 64 ) * NN + irow] = acc4[r];
        nb[(size_t)(fr + 80 ) * NN + irow] = acc5[r];
        nb[(size_t)(fr + 96 ) * NN + irow] = acc6[r];
        nb[(size_t)(fr + 112) * NN + irow] = acc7[r];
    }
    dacc += __shfl_xor(dacc, 16);
    dacc += __shfl_xor(dacc, 32);
    if (l < 16) dpart[(size_t)chunk * NN + i0 + wv * 16 + l] = dacc;
}

// ---------------------------------------------------------------------------
// Pass C: out[i][f] = elu( sum_c numw[c][f][i] / sum_c dpart[c][i] )
// ---------------------------------------------------------------------------
__global__ __launch_bounds__(256)
void gat_reduce(const float* __restrict__ numw, const float* __restrict__ dpart,
                float* __restrict__ out, int nchunk) {
    __shared__ float tile[FOUT * 33];
    __shared__ float dent[32];
    const int t = threadIdx.x;
    const int i0 = blockIdx.x * 32;
    if (t < 32) {
        float d = 0.f;
        for (int c = 0; c < nchunk; ++c) d += dpart[(size_t)c * NN + i0 + t];
        dent[t] = d;
    }
    __syncthreads();
    #pragma unroll
    for (int e = 0; e < 4; ++e) {
        const int f = e * 32 + (t >> 3);
        const int io = (t & 7) * 4;
        float4 s = {0.f, 0.f, 0.f, 0.f};
        for (int c = 0; c < nchunk; ++c) {
            const float4 v = *(const float4*)(numw + ((size_t)c * FOUT + f) * NN + i0 + io);
            s.x += v.x; s.y += v.y; s.z += v.z; s.w += v.w;
        }
        float v;
        v = s.x / dent[io + 0]; tile[f * 33 + io + 0] = (v > 0.f) ? v : expm1f(v);
        v = s.y / dent[io + 1]; tile[f * 33 + io + 1] = (v > 0.f) ? v : expm1f(v);
        v = s.z / dent[io + 2]; tile[f * 33 + io + 2] = (v > 0.f) ? v : expm1f(v);
        v = s.w / dent[io + 3]; tile[f * 33 + io + 3] = (v > 0.f) ? v : expm1f(v);
    }
    __syncthreads();
    #pragma unroll
    for (int e = 0; e < 4; ++e) {
        const int row = (t >> 5) * 4 + e;
        const int fo = (t & 31) * 4;
        const float4 v = { tile[(fo + 0) * 33 + row], tile[(fo + 1) * 33 + row],
                           tile[(fo + 2) * 33 + row], tile[(fo + 3) * 33 + row] };
        *(float4*)(out + (size_t)(i0 + row) * FOUT + fo) = v;
    }
}

// ---------------------------------------------------------------------------
extern "C" void kernel_launch(void* const* d_in, const int* in_sizes, int n_in,
                              void* d_out, int out_size, void* d_ws, size_t ws_size,
                              hipStream_t stream) {
    const float* input = (const float*)d_in[0];
    const int*   adj   = (const int*)d_in[1];
    const float* Ww    = (const float*)d_in[2];
    const float* Wb    = (const float*)d_in[3];
    const float* aw    = (const float*)d_in[4];
    const float* ab    = (const float*)d_in[5];
    float* out = (float*)d_out;

    char* ws = (char*)d_ws;
    unsigned short* hT4 = (unsigned short*)ws;               // 2 MB
    float* s_buf = (float*)(ws + (size_t)FOUT * NN * 2);     // 32 KB
    float* t_buf = s_buf + NN;                               // 32 KB
    float* dpart = t_buf + NN;                               // NCH*32 KB
    float* numw = dpart + (size_t)NCH * NN;                  // NCH*4 MB
    u64* bm3 = (u64*)(numw + (size_t)NCH * NN * FOUT);       // 8 MB

    gat_pass_a<<<dim3(NN / 64), 256, 0, stream>>>(input, Ww, Wb, aw, ab, hT4, s_buf, t_buf);
    gat_compress<<<dim3(NN / 2), 256, 0, stream>>>(adj, bm3);
    gat_pass_b<<<dim3(NN / 64, NCH), 256, 0, stream>>>(bm3, hT4, s_buf, t_buf, numw, dpart);
    gat_reduce<<<dim3(NN / 32), 256, 0, stream>>>(numw, dpart, out, NCH);
}